// Round 1
// baseline (391.934 us; speedup 1.0000x reference)
//
#include <hip/hip_runtime.h>
#include <hip/hip_bf16.h>

#define DIM  1024
#define RANK 32
#define BATCH 4
#define SEQ  4096
#define MTOT (BATCH * SEQ)   // 16384

typedef short bf16x8 __attribute__((ext_vector_type(8)));          // MFMA A/B frag (8 bf16)
typedef float f32x4 __attribute__((ext_vector_type(4)));           // 16x16 MFMA C/D frag
typedef float f32x16 __attribute__((ext_vector_type(16)));         // 32x32 MFMA C/D frag
typedef unsigned short ushort8v __attribute__((ext_vector_type(8)));
typedef unsigned int uint2v __attribute__((ext_vector_type(2)));

__device__ inline unsigned short f2bf(float f) {
    union { float f; unsigned int u; } v; v.f = f;
    return (unsigned short)((v.u + 0x7FFFu + ((v.u >> 16) & 1u)) >> 16);  // RNE
}

__device__ inline unsigned int pk_bf16(float a, float b) {
    __hip_bfloat162 h = __float22bfloat162_rn(make_float2(a, b));
    unsigned int u; __builtin_memcpy(&u, &h, 4);
    return u;
}

// async global->LDS, 16B per lane; data lands at lds_base + lane*16 (wave-uniform base)
__device__ inline void gl_lds16(const unsigned short* g, unsigned short* l) {
    __builtin_amdgcn_global_load_lds(
        (const __attribute__((address_space(1))) unsigned int*)g,
        (__attribute__((address_space(3))) unsigned int*)l, 16, 0, 0);
}

// ---------------- K0: pack Q*SC, K (fp32 32x1024 each) -> wqk bf16 (64x1024) -----------
__global__ __launch_bounds__(256) void k_cvt_qk(const float* __restrict__ Q,
                                                const float* __restrict__ K,
                                                unsigned short* __restrict__ wqk) {
    int i = blockIdx.x * 256 + threadIdx.x;        // 65536 total
    int row = i >> 10, col = i & 1023;
    const float SC = 0.045084220027779984f;        // 1/(32*ln2)
    float v = (row < RANK) ? Q[row * DIM + col] * SC : K[(row - RANK) * DIM + col];
    wqk[i] = f2bf(v);
}

// ---------------- K1: tiled transpose + fp32->bf16 (VO -> vot[e][d]) -------------------
__global__ __launch_bounds__(256) void k_transpose_cvt(const float* __restrict__ in,
                                                       unsigned short* __restrict__ out,
                                                       int R, int C) {
    __shared__ float tile[64][65];
    const int tid = threadIdx.x;
    const int c0 = blockIdx.x * 64, r0 = blockIdx.y * 64;
    {
        int c = (tid & 15) * 4;
#pragma unroll
        for (int i = 0; i < 4; ++i) {
            int r = (tid >> 4) + i * 16;
            f32x4 v = *(const f32x4*)(in + (size_t)(r0 + r) * C + c0 + c);
            tile[r][c + 0] = v[0]; tile[r][c + 1] = v[1];
            tile[r][c + 2] = v[2]; tile[r][c + 3] = v[3];
        }
    }
    __syncthreads();
    {
        int r = (tid & 15) * 4;
#pragma unroll
        for (int i = 0; i < 4; ++i) {
            int c = (tid >> 4) + i * 16;
            unsigned short o0 = f2bf(tile[r + 0][c]), o1 = f2bf(tile[r + 1][c]);
            unsigned short o2 = f2bf(tile[r + 2][c]), o3 = f2bf(tile[r + 3][c]);
            unsigned short* p = out + (size_t)(c0 + c) * R + r0 + r;
            p[0] = o0; p[1] = o1; p[2] = o2; p[3] = o3;
        }
    }
}

// ---------------- K2: x fp32 -> xbf bf16, row-major passthrough ------------------------
__global__ __launch_bounds__(256) void k_xbf(const float* __restrict__ x,
                                             unsigned short* __restrict__ xbf) {
    size_t i = ((size_t)blockIdx.x * 256 + threadIdx.x) * 8;
    f32x4 v0 = *(const f32x4*)(x + i);
    f32x4 v1 = *(const f32x4*)(x + i + 4);
    ushort8v o;
    o[0] = f2bf(v0[0]); o[1] = f2bf(v0[1]); o[2] = f2bf(v0[2]); o[3] = f2bf(v0[3]);
    o[4] = f2bf(v1[0]); o[5] = f2bf(v1[1]); o[6] = f2bf(v1[2]); o[7] = f2bf(v1[3]);
    *(ushort8v*)(xbf + i) = o;
}

// ---------------- K3: xqk = xbf @ wqk^T  (M=16384, N=64, K=1024), bf16 out -------------
__global__ __launch_bounds__(256) void k_proj(const unsigned short* __restrict__ xbf,
                                              const unsigned short* __restrict__ wqk,
                                              unsigned short* __restrict__ xqk) {
    __shared__ __align__(16) unsigned short a_lds[128 * 32];
    __shared__ __align__(16) unsigned short w_lds[64 * 32];
    const int tid = threadIdx.x;
    const int w = tid >> 6, lane = tid & 63, l15 = lane & 15, quad = lane >> 4;
    const int wm = w & 1, wn = w >> 1;
    const int rowbase = blockIdx.x * 128;

    f32x4 acc[4][2];
#pragma unroll
    for (int mt = 0; mt < 4; ++mt)
#pragma unroll
        for (int nt = 0; nt < 2; ++nt) acc[mt][nt] = (f32x4){0.f, 0.f, 0.f, 0.f};

    const unsigned short* Ab = xbf + (size_t)(rowbase + w * 32 + (lane >> 2)) * DIM + (lane & 3) * 8;
    const unsigned short* Wb = wqk + (size_t)(w * 16 + (lane >> 2)) * DIM + (lane & 3) * 8;

    for (int k0 = 0; k0 < DIM; k0 += 32) {
        gl_lds16(Ab + k0, &a_lds[(w * 32) * 32]);
        gl_lds16(Ab + (size_t)16 * DIM + k0, &a_lds[(w * 32 + 16) * 32]);
        gl_lds16(Wb + k0, &w_lds[(w * 16) * 32]);
        __syncthreads();
        bf16x8 am[4], bn[2];
#pragma unroll
        for (int mt = 0; mt < 4; ++mt)
            am[mt] = *(const bf16x8*)&a_lds[(wm * 64 + mt * 16 + l15) * 32 + quad * 8];
#pragma unroll
        for (int nt = 0; nt < 2; ++nt)
            bn[nt] = *(const bf16x8*)&w_lds[(wn * 32 + nt * 16 + l15) * 32 + quad * 8];
#pragma unroll
        for (int mt = 0; mt < 4; ++mt)
#pragma unroll
            for (int nt = 0; nt < 2; ++nt)
                acc[mt][nt] = __builtin_amdgcn_mfma_f32_16x16x32_bf16(am[mt], bn[nt], acc[mt][nt], 0, 0, 0);
        __syncthreads();
    }
#pragma unroll
    for (int mt = 0; mt < 4; ++mt)
#pragma unroll
        for (int nt = 0; nt < 2; ++nt)
#pragma unroll
            for (int r = 0; r < 4; ++r) {
                int grow = rowbase + wm * 64 + mt * 16 + quad * 4 + r;
                xqk[(size_t)grow * 64 + wn * 32 + nt * 16 + l15] = f2bf(acc[mt][nt][r]);
            }
}

// ---------------- K4: P = exp2(xq . xk) bf16 (materialized), den partials --------------
__global__ __launch_bounds__(256) void k_score(const unsigned short* __restrict__ xqk,
                                               unsigned short* __restrict__ P,
                                               float* __restrict__ den_part) {
    __shared__ __align__(16) unsigned short xk_lds[128 * 32];
    __shared__ __align__(16) unsigned short p_lds[64 * 136];
    __shared__ float denp[4][64];
    const int tid = threadIdx.x;
    const int w = tid >> 6, lane = tid & 63, l31 = lane & 31, half = lane >> 5;
    const int qbase = blockIdx.x * 64;
    const int kc = blockIdx.y;
    const int b = blockIdx.z;

    bf16x8 bq[2][2];
#pragma unroll
    for (int qt = 0; qt < 2; ++qt) {
        const unsigned short* base = xqk + (size_t)(b * SEQ + qbase + qt * 32 + l31) * 64 + half * 8;
        bq[qt][0] = *(const bf16x8*)(base);
        bq[qt][1] = *(const bf16x8*)(base + 16);
    }
    float dacc[2] = {0.f, 0.f};

    const unsigned short* XKb = xqk + (size_t)(b * SEQ + kc * 512 + w * 32 + (lane >> 2)) * 64 + 32 + (lane & 3) * 8;

    for (int it = 0; it < 4; ++it) {
        const int kkey = kc * 512 + it * 128;
        gl_lds16(XKb + (size_t)(it * 128) * 64, &xk_lds[(w * 32) * 32]);
        gl_lds16(XKb + (size_t)(it * 128 + 16) * 64, &xk_lds[(w * 32 + 16) * 32]);
        __syncthreads();

        bf16x8 ak0 = *(const bf16x8*)&xk_lds[(w * 32 + l31) * 32 + half * 8];
        bf16x8 ak1 = *(const bf16x8*)&xk_lds[(w * 32 + l31) * 32 + 16 + half * 8];
        f32x16 z;
#pragma unroll
        for (int i = 0; i < 16; ++i) z[i] = 0.f;
#pragma unroll
        for (int qt = 0; qt < 2; ++qt) {
            f32x16 sc = __builtin_amdgcn_mfma_f32_32x32x16_bf16(ak0, bq[qt][0], z, 0, 0, 0);
            sc = __builtin_amdgcn_mfma_f32_32x32x16_bf16(ak1, bq[qt][1], sc, 0, 0, 0);
#pragma unroll
            for (int g = 0; g < 4; ++g) {
                float e0 = exp2f(sc[4 * g + 0]), e1 = exp2f(sc[4 * g + 1]);
                float e2 = exp2f(sc[4 * g + 2]), e3 = exp2f(sc[4 * g + 3]);
                dacc[qt] += (e0 + e1) + (e2 + e3);
                uint2v dw; dw[0] = pk_bf16(e0, e1); dw[1] = pk_bf16(e2, e3);
                *(uint2v*)&p_lds[(qt * 32 + l31) * 136 + w * 32 + g * 8 + half * 4] = dw;
            }
        }
        __syncthreads();
#pragma unroll
        for (int i = 0; i < 4; ++i) {
            int row = i * 16 + (tid >> 4);
            int col = (tid & 15) * 8;
            ushort8v v = *(const ushort8v*)&p_lds[row * 136 + col];
            *(ushort8v*)(P + (size_t)(b * SEQ + qbase + row) * SEQ + kkey + col) = v;
        }
    }
#pragma unroll
    for (int qt = 0; qt < 2; ++qt) {
        float d = dacc[qt];
        d += __shfl_xor(d, 32);
        if (half == 0) denp[w][qt * 32 + l31] = d;
    }
    __syncthreads();
    if (tid < 64) {
        float s = denp[0][tid] + denp[1][tid] + denp[2][tid] + denp[3][tid];
        den_part[(size_t)kc * MTOT + b * SEQ + qbase + tid] = s;
    }
}

// ---------------- K5 v3: xvoT[b][e][u] = (x @ VO)^T. 128e x 256u tile, BK=64, 32x32 ----
// T3+T4 pipeline: 3 LDS buffers, prefetch depth 2, counted s_waitcnt vmcnt(12) — the
// just-issued prefetches stay in flight across both barriers; never drain mid-loop.
// XOR chunk swizzle: staged slot s holds global chunk s^(row&7); frag read uses
// slot (ks*2+half)^(l31&7) -> conflict-free-as-possible b128.
__global__ __launch_bounds__(512, 2) void k_xvo(const unsigned short* __restrict__ vot,
                                                const unsigned short* __restrict__ xbf,
                                                unsigned short* __restrict__ xvoT) {
    __shared__ __align__(16) unsigned short a_lds[3][128 * 64];   // 3 x 16 KB
    __shared__ __align__(16) unsigned short b_lds[3][256 * 64];   // 3 x 32 KB  (total 144 KB)
    const int tid = threadIdx.x;
    const int w = tid >> 6, lane = tid & 63, l31 = lane & 31, half = lane >> 5;
    const int wm = w & 1, wn = w >> 1;
    const int ubase = blockIdx.x * 256;
    const int ebase = blockIdx.y * 128;
    const int b = blockIdx.z;

    f32x16 acc[2][2];
#pragma unroll
    for (int at = 0; at < 2; ++at)
#pragma unroll
        for (int bt = 0; bt < 2; ++bt)
#pragma unroll
            for (int i = 0; i < 16; ++i) acc[at][bt][i] = 0.f;

    const int sub = lane >> 3;                 // 0..7 rows within a stage call
    const int g = (lane & 7) ^ (sub & 7);      // swizzled global chunk for this lane
    const unsigned short* Ap = vot + (size_t)(ebase + w * 16 + sub) * DIM + g * 8;
    const unsigned short* Bp = xbf + (size_t)(b * SEQ + ubase + w * 32 + sub) * DIM + g * 8;

    // 6 gl_lds per wave per tile (2 A + 4 B) — vmcnt counts below rely on this.
    auto stage = [&](int sb, int k0) {
#pragma unroll
        for (int c = 0; c < 2; ++c)
            gl_lds16(Ap + (size_t)(c * 8) * DIM + k0, &a_lds[sb][(w * 16 + c * 8) * 64]);
#pragma unroll
        for (int c = 0; c < 4; ++c)
            gl_lds16(Bp + (size_t)(c * 8) * DIM + k0, &b_lds[sb][(w * 32 + c * 8) * 64]);
    };

    const int NT = DIM / 64;                   // 16
    stage(0, 0);
    stage(1, 64);
    int cur = 0;
    for (int t = 0; t < NT; ++t) {
        if (t + 2 < NT) {
            int sb = cur - 1; if (sb < 0) sb = 2;           // (cur+2)%3
            stage(sb, (t + 2) * 64);
            asm volatile("s_waitcnt vmcnt(12)" ::: "memory");  // drain tile t only
        } else if (t + 1 < NT) {
            asm volatile("s_waitcnt vmcnt(6)" ::: "memory");
        } else {
            asm volatile("s_waitcnt vmcnt(0)" ::: "memory");
        }
        __builtin_amdgcn_s_barrier();
        asm volatile("" ::: "memory");

        const unsigned short* al = a_lds[cur];
        const unsigned short* bl = b_lds[cur];
        const int abase = (wm * 64 + l31) * 64;
        const int bbase = (wn * 64 + l31) * 64;
        __builtin_amdgcn_s_setprio(1);
#pragma unroll
        for (int ks = 0; ks < 4; ++ks) {
            const int soff = ((ks * 2 + half) ^ (l31 & 7)) * 8;
            bf16x8 a0 = *(const bf16x8*)&al[abase + soff];
            bf16x8 a1 = *(const bf16x8*)&al[abase + 2048 + soff];
            bf16x8 b0 = *(const bf16x8*)&bl[bbase + soff];
            bf16x8 b1 = *(const bf16x8*)&bl[bbase + 2048 + soff];
            acc[0][0] = __builtin_amdgcn_mfma_f32_32x32x16_bf16(a0, b0, acc[0][0], 0, 0, 0);
            acc[0][1] = __builtin_amdgcn_mfma_f32_32x32x16_bf16(a0, b1, acc[0][1], 0, 0, 0);
            acc[1][0] = __builtin_amdgcn_mfma_f32_32x32x16_bf16(a1, b0, acc[1][0], 0, 0, 0);
            acc[1][1] = __builtin_amdgcn_mfma_f32_32x32x16_bf16(a1, b1, acc[1][1], 0, 0, 0);
        }
        __builtin_amdgcn_s_setprio(0);
        asm volatile("" ::: "memory");
        __builtin_amdgcn_s_barrier();             // all reads of buf[cur] done before overwrite
        asm volatile("" ::: "memory");
        cur = (cur == 2) ? 0 : cur + 1;
    }
#pragma unroll
    for (int at = 0; at < 2; ++at)
#pragma unroll
        for (int bt = 0; bt < 2; ++bt)
#pragma unroll
            for (int reg = 0; reg < 16; ++reg) {
                int lr = wm * 64 + at * 32 + (reg & 3) + 8 * (reg >> 2) + 4 * half;
                int u = ubase + wn * 64 + bt * 32 + l31;
                xvoT[(size_t)(b * DIM + ebase + lr) * SEQ + u] = f2bf(acc[at][bt][reg]);
            }
}

// ---------------- K6 v3: out = (P @ xvoT^T)*(1/den). 128q x 256e tile, BK=64, 32x32 ----
// Same T3+T4 pipeline as K5 v3. 1-D grid 512, XCD swizzle: xcd=p&7 owns rows
// 16*xcd..+15 (all 4 e-tiles co-located on one XCD's L2).
__global__ __launch_bounds__(512, 2) void k_pv(const unsigned short* __restrict__ P,
                                               const unsigned short* __restrict__ xvoT,
                                               const float* __restrict__ den_part,
                                               float* __restrict__ out) {
    __shared__ __align__(16) unsigned short a_lds[3][128 * 64];   // 3 x 16 KB
    __shared__ __align__(16) unsigned short b_lds[3][256 * 64];   // 3 x 32 KB
    __shared__ float rden[128];
    const int tid = threadIdx.x;
    const int w = tid >> 6, lane = tid & 63, l31 = lane & 31, half = lane >> 5;
    const int wm = w & 1, wn = w >> 1;

    const int p = blockIdx.x;
    const int xcd = p & 7, t0 = p >> 3;
    const int rowtile = xcd * 16 + (t0 >> 2);  // 0..127
    const int etile = t0 & 3;                  // 0..3
    const int rowbase = rowtile * 128;         // global q-row
    const int ebase = etile * 256;
    const int b = rowbase >> 12;

    if (tid < 128) {
        float s = 0.f;
#pragma unroll
        for (int i = 0; i < 8; ++i) s += den_part[(size_t)i * MTOT + rowbase + tid];
        rden[tid] = 1.0f / s;
    }
    // den loads retired (data-dep wait above); LDS write drained so vmcnt counts in
    // the pipeline below see exactly the gl_lds traffic.
    asm volatile("s_waitcnt lgkmcnt(0)" ::: "memory");

    f32x16 acc[2][2];
#pragma unroll
    for (int at = 0; at < 2; ++at)
#pragma unroll
        for (int bt = 0; bt < 2; ++bt)
#pragma unroll
            for (int i = 0; i < 16; ++i) acc[at][bt][i] = 0.f;

    const int sub = lane >> 3;
    const int g = (lane & 7) ^ (sub & 7);
    const unsigned short* Ap = P + (size_t)(rowbase + w * 16 + sub) * SEQ + g * 8;
    const unsigned short* Bp = xvoT + (size_t)(b * DIM + ebase + w * 32 + sub) * SEQ + g * 8;

    auto stage = [&](int sb, int k0) {
#pragma unroll
        for (int c = 0; c < 2; ++c)
            gl_lds16(Ap + (size_t)(c * 8) * SEQ + k0, &a_lds[sb][(w * 16 + c * 8) * 64]);
#pragma unroll
        for (int c = 0; c < 4; ++c)
            gl_lds16(Bp + (size_t)(c * 8) * SEQ + k0, &b_lds[sb][(w * 32 + c * 8) * 64]);
    };

    const int NT = SEQ / 64;                   // 64
    stage(0, 0);
    stage(1, 64);
    int cur = 0;
    for (int t = 0; t < NT; ++t) {
        if (t + 2 < NT) {
            int sb = cur - 1; if (sb < 0) sb = 2;           // (cur+2)%3
            stage(sb, (t + 2) * 64);
            asm volatile("s_waitcnt vmcnt(12)" ::: "memory");  // drain tile t only
        } else if (t + 1 < NT) {
            asm volatile("s_waitcnt vmcnt(6)" ::: "memory");
        } else {
            asm volatile("s_waitcnt vmcnt(0)" ::: "memory");
        }
        __builtin_amdgcn_s_barrier();
        asm volatile("" ::: "memory");

        const unsigned short* al = a_lds[cur];
        const unsigned short* bl = b_lds[cur];
        const int abase = (wm * 64 + l31) * 64;
        const int bbase = (wn * 64 + l31) * 64;
        __builtin_amdgcn_s_setprio(1);
#pragma unroll
        for (int ks = 0; ks < 4; ++ks) {
            const int soff = ((ks * 2 + half) ^ (l31 & 7)) * 8;
            bf16x8 a0 = *(const bf16x8*)&al[abase + soff];
            bf16x8 a1 = *(const bf16x8*)&al[abase + 2048 + soff];
            bf16x8 b0 = *(const bf16x8*)&bl[bbase + soff];
            bf16x8 b1 = *(const bf16x8*)&bl[bbase + 2048 + soff];
            acc[0][0] = __builtin_amdgcn_mfma_f32_32x32x16_bf16(a0, b0, acc[0][0], 0, 0, 0);
            acc[0][1] = __builtin_amdgcn_mfma_f32_32x32x16_bf16(a0, b1, acc[0][1], 0, 0, 0);
            acc[1][0] = __builtin_amdgcn_mfma_f32_32x32x16_bf16(a1, b0, acc[1][0], 0, 0, 0);
            acc[1][1] = __builtin_amdgcn_mfma_f32_32x32x16_bf16(a1, b1, acc[1][1], 0, 0, 0);
        }
        __builtin_amdgcn_s_setprio(0);
        asm volatile("" ::: "memory");
        __builtin_amdgcn_s_barrier();
        asm volatile("" ::: "memory");
        cur = (cur == 2) ? 0 : cur + 1;
    }
#pragma unroll
    for (int at = 0; at < 2; ++at)
#pragma unroll
        for (int bt = 0; bt < 2; ++bt)
#pragma unroll
            for (int reg = 0; reg < 16; ++reg) {
                int lr = wm * 64 + at * 32 + (reg & 3) + 8 * (reg >> 2) + 4 * half;
                int e = ebase + wn * 64 + bt * 32 + l31;
                out[(size_t)(rowbase + lr) * DIM + e] = acc[at][bt][reg] * rden[lr];
            }
}

extern "C" void kernel_launch(void* const* d_in, const int* in_sizes, int n_in,
                              void* d_out, int out_size, void* d_ws, size_t ws_size,
                              hipStream_t stream) {
    const float* x  = (const float*)d_in[0];
    const float* Q  = (const float*)d_in[1];
    const float* K  = (const float*)d_in[2];
    const float* VO = (const float*)d_in[3];
    float* out = (float*)d_out;

    char* ws = (char*)d_ws;
    unsigned short* wqk  = (unsigned short*)(ws + 0);           // 64x1024 bf16        128 KB
    unsigned short* vot  = (unsigned short*)(ws + 131072);      // 1024x1024 bf16        2 MB
    unsigned short* xqk  = (unsigned short*)(ws + 2228224);     // 16384x64 bf16         2 MB
    unsigned short* xbf  = (unsigned short*)(ws + 4325376);     // 16384x1024 bf16      32 MB
    unsigned short* xvoT = (unsigned short*)(ws + 37879808);    // 4x1024x4096 bf16     32 MB
    float*          denp = (float*)(ws + 71434240);             // 8x16384 fp32        512 KB
    unsigned short* P    = (unsigned short*)(ws + 71958528);    // 4x4096x4096 bf16    128 MB

    k_cvt_qk<<<256, 256, 0, stream>>>(Q, K, wqk);
    k_transpose_cvt<<<dim3(16, 16, 1), 256, 0, stream>>>(VO, vot, 1024, 1024);
    k_xbf<<<8192, 256, 0, stream>>>(x, xbf);
    k_proj<<<128, 256, 0, stream>>>(xbf, wqk, xqk);
    k_score<<<dim3(SEQ / 64, 8, BATCH), 256, 0, stream>>>(xqk, P, denp);
    k_xvo<<<dim3(16, 8, BATCH), 512, 0, stream>>>(vot, xbf, xvoT);
    k_pv<<<dim3(512, 1, 1), 512, 0, stream>>>(P, xvoT, denp, out);
}

// Round 2
// 361.676 us; speedup vs baseline: 1.0837x; 1.0837x over previous
//
#include <hip/hip_runtime.h>
#include <hip/hip_bf16.h>

#define DIM  1024
#define RANK 32
#define BATCH 4
#define SEQ  4096
#define MTOT (BATCH * SEQ)   // 16384

typedef short bf16x8 __attribute__((ext_vector_type(8)));          // MFMA A/B frag (8 bf16)
typedef float f32x4 __attribute__((ext_vector_type(4)));           // 16x16 MFMA C/D frag
typedef float f32x16 __attribute__((ext_vector_type(16)));         // 32x32 MFMA C/D frag
typedef unsigned short ushort8v __attribute__((ext_vector_type(8)));
typedef unsigned int uint2v __attribute__((ext_vector_type(2)));

__device__ inline unsigned short f2bf(float f) {
    union { float f; unsigned int u; } v; v.f = f;
    return (unsigned short)((v.u + 0x7FFFu + ((v.u >> 16) & 1u)) >> 16);  // RNE
}

__device__ inline unsigned int pk_bf16(float a, float b) {
    __hip_bfloat162 h = __float22bfloat162_rn(make_float2(a, b));
    unsigned int u; __builtin_memcpy(&u, &h, 4);
    return u;
}

// async global->LDS, 16B per lane; data lands at lds_base + lane*16 (wave-uniform base)
__device__ inline void gl_lds16(const unsigned short* g, unsigned short* l) {
    __builtin_amdgcn_global_load_lds(
        (const __attribute__((address_space(1))) unsigned int*)g,
        (__attribute__((address_space(3))) unsigned int*)l, 16, 0, 0);
}

// ---------------- K0: pack Q*SC, K (fp32 32x1024 each) -> wqk bf16 (64x1024) -----------
__global__ __launch_bounds__(256) void k_cvt_qk(const float* __restrict__ Q,
                                                const float* __restrict__ K,
                                                unsigned short* __restrict__ wqk) {
    int i = blockIdx.x * 256 + threadIdx.x;        // 65536 total
    int row = i >> 10, col = i & 1023;
    const float SC = 0.045084220027779984f;        // 1/(32*ln2)
    float v = (row < RANK) ? Q[row * DIM + col] * SC : K[(row - RANK) * DIM + col];
    wqk[i] = f2bf(v);
}

// ---------------- K1: tiled transpose + fp32->bf16 (VO -> vot[e][d]) -------------------
__global__ __launch_bounds__(256) void k_transpose_cvt(const float* __restrict__ in,
                                                       unsigned short* __restrict__ out,
                                                       int R, int C) {
    __shared__ float tile[64][65];
    const int tid = threadIdx.x;
    const int c0 = blockIdx.x * 64, r0 = blockIdx.y * 64;
    {
        int c = (tid & 15) * 4;
#pragma unroll
        for (int i = 0; i < 4; ++i) {
            int r = (tid >> 4) + i * 16;
            f32x4 v = *(const f32x4*)(in + (size_t)(r0 + r) * C + c0 + c);
            tile[r][c + 0] = v[0]; tile[r][c + 1] = v[1];
            tile[r][c + 2] = v[2]; tile[r][c + 3] = v[3];
        }
    }
    __syncthreads();
    {
        int r = (tid & 15) * 4;
#pragma unroll
        for (int i = 0; i < 4; ++i) {
            int c = (tid >> 4) + i * 16;
            unsigned short o0 = f2bf(tile[r + 0][c]), o1 = f2bf(tile[r + 1][c]);
            unsigned short o2 = f2bf(tile[r + 2][c]), o3 = f2bf(tile[r + 3][c]);
            unsigned short* p = out + (size_t)(c0 + c) * R + r0 + r;
            p[0] = o0; p[1] = o1; p[2] = o2; p[3] = o3;
        }
    }
}

// ---------------- K2: x fp32 -> xbf bf16, row-major passthrough ------------------------
__global__ __launch_bounds__(256) void k_xbf(const float* __restrict__ x,
                                             unsigned short* __restrict__ xbf) {
    size_t i = ((size_t)blockIdx.x * 256 + threadIdx.x) * 8;
    f32x4 v0 = *(const f32x4*)(x + i);
    f32x4 v1 = *(const f32x4*)(x + i + 4);
    ushort8v o;
    o[0] = f2bf(v0[0]); o[1] = f2bf(v0[1]); o[2] = f2bf(v0[2]); o[3] = f2bf(v0[3]);
    o[4] = f2bf(v1[0]); o[5] = f2bf(v1[1]); o[6] = f2bf(v1[2]); o[7] = f2bf(v1[3]);
    *(ushort8v*)(xbf + i) = o;
}

// ---------------- K3: xqk = xbf @ wqk^T  (M=16384, N=64, K=1024), bf16 out -------------
__global__ __launch_bounds__(256) void k_proj(const unsigned short* __restrict__ xbf,
                                              const unsigned short* __restrict__ wqk,
                                              unsigned short* __restrict__ xqk) {
    __shared__ __align__(16) unsigned short a_lds[128 * 32];
    __shared__ __align__(16) unsigned short w_lds[64 * 32];
    const int tid = threadIdx.x;
    const int w = tid >> 6, lane = tid & 63, l15 = lane & 15, quad = lane >> 4;
    const int wm = w & 1, wn = w >> 1;
    const int rowbase = blockIdx.x * 128;

    f32x4 acc[4][2];
#pragma unroll
    for (int mt = 0; mt < 4; ++mt)
#pragma unroll
        for (int nt = 0; nt < 2; ++nt) acc[mt][nt] = (f32x4){0.f, 0.f, 0.f, 0.f};

    const unsigned short* Ab = xbf + (size_t)(rowbase + w * 32 + (lane >> 2)) * DIM + (lane & 3) * 8;
    const unsigned short* Wb = wqk + (size_t)(w * 16 + (lane >> 2)) * DIM + (lane & 3) * 8;

    for (int k0 = 0; k0 < DIM; k0 += 32) {
        gl_lds16(Ab + k0, &a_lds[(w * 32) * 32]);
        gl_lds16(Ab + (size_t)16 * DIM + k0, &a_lds[(w * 32 + 16) * 32]);
        gl_lds16(Wb + k0, &w_lds[(w * 16) * 32]);
        __syncthreads();
        bf16x8 am[4], bn[2];
#pragma unroll
        for (int mt = 0; mt < 4; ++mt)
            am[mt] = *(const bf16x8*)&a_lds[(wm * 64 + mt * 16 + l15) * 32 + quad * 8];
#pragma unroll
        for (int nt = 0; nt < 2; ++nt)
            bn[nt] = *(const bf16x8*)&w_lds[(wn * 32 + nt * 16 + l15) * 32 + quad * 8];
#pragma unroll
        for (int mt = 0; mt < 4; ++mt)
#pragma unroll
            for (int nt = 0; nt < 2; ++nt)
                acc[mt][nt] = __builtin_amdgcn_mfma_f32_16x16x32_bf16(am[mt], bn[nt], acc[mt][nt], 0, 0, 0);
        __syncthreads();
    }
#pragma unroll
    for (int mt = 0; mt < 4; ++mt)
#pragma unroll
        for (int nt = 0; nt < 2; ++nt)
#pragma unroll
            for (int r = 0; r < 4; ++r) {
                int grow = rowbase + wm * 64 + mt * 16 + quad * 4 + r;
                xqk[(size_t)grow * 64 + wn * 32 + nt * 16 + l15] = f2bf(acc[mt][nt][r]);
            }
}

// ---------------- K4: P = exp2(xq . xk) bf16 (materialized), den partials --------------
__global__ __launch_bounds__(256) void k_score(const unsigned short* __restrict__ xqk,
                                               unsigned short* __restrict__ P,
                                               float* __restrict__ den_part) {
    __shared__ __align__(16) unsigned short xk_lds[128 * 32];
    __shared__ __align__(16) unsigned short p_lds[64 * 136];
    __shared__ float denp[4][64];
    const int tid = threadIdx.x;
    const int w = tid >> 6, lane = tid & 63, l31 = lane & 31, half = lane >> 5;
    const int qbase = blockIdx.x * 64;
    const int kc = blockIdx.y;
    const int b = blockIdx.z;

    bf16x8 bq[2][2];
#pragma unroll
    for (int qt = 0; qt < 2; ++qt) {
        const unsigned short* base = xqk + (size_t)(b * SEQ + qbase + qt * 32 + l31) * 64 + half * 8;
        bq[qt][0] = *(const bf16x8*)(base);
        bq[qt][1] = *(const bf16x8*)(base + 16);
    }
    float dacc[2] = {0.f, 0.f};

    const unsigned short* XKb = xqk + (size_t)(b * SEQ + kc * 512 + w * 32 + (lane >> 2)) * 64 + 32 + (lane & 3) * 8;

    for (int it = 0; it < 4; ++it) {
        const int kkey = kc * 512 + it * 128;
        gl_lds16(XKb + (size_t)(it * 128) * 64, &xk_lds[(w * 32) * 32]);
        gl_lds16(XKb + (size_t)(it * 128 + 16) * 64, &xk_lds[(w * 32 + 16) * 32]);
        __syncthreads();

        bf16x8 ak0 = *(const bf16x8*)&xk_lds[(w * 32 + l31) * 32 + half * 8];
        bf16x8 ak1 = *(const bf16x8*)&xk_lds[(w * 32 + l31) * 32 + 16 + half * 8];
        f32x16 z;
#pragma unroll
        for (int i = 0; i < 16; ++i) z[i] = 0.f;
#pragma unroll
        for (int qt = 0; qt < 2; ++qt) {
            f32x16 sc = __builtin_amdgcn_mfma_f32_32x32x16_bf16(ak0, bq[qt][0], z, 0, 0, 0);
            sc = __builtin_amdgcn_mfma_f32_32x32x16_bf16(ak1, bq[qt][1], sc, 0, 0, 0);
#pragma unroll
            for (int g = 0; g < 4; ++g) {
                float e0 = exp2f(sc[4 * g + 0]), e1 = exp2f(sc[4 * g + 1]);
                float e2 = exp2f(sc[4 * g + 2]), e3 = exp2f(sc[4 * g + 3]);
                dacc[qt] += (e0 + e1) + (e2 + e3);
                uint2v dw; dw[0] = pk_bf16(e0, e1); dw[1] = pk_bf16(e2, e3);
                *(uint2v*)&p_lds[(qt * 32 + l31) * 136 + w * 32 + g * 8 + half * 4] = dw;
            }
        }
        __syncthreads();
#pragma unroll
        for (int i = 0; i < 4; ++i) {
            int row = i * 16 + (tid >> 4);
            int col = (tid & 15) * 8;
            ushort8v v = *(const ushort8v*)&p_lds[row * 136 + col];
            *(ushort8v*)(P + (size_t)(b * SEQ + qbase + row) * SEQ + kkey + col) = v;
        }
    }
#pragma unroll
    for (int qt = 0; qt < 2; ++qt) {
        float d = dacc[qt];
        d += __shfl_xor(d, 32);
        if (half == 0) denp[w][qt * 32 + l31] = d;
    }
    __syncthreads();
    if (tid < 64) {
        float s = denp[0][tid] + denp[1][tid] + denp[2][tid] + denp[3][tid];
        den_part[(size_t)kc * MTOT + b * SEQ + qbase + tid] = s;
    }
}

// ---------------- K5 v4: xvoT[b][e][u] = (x @ VO)^T. 128e x 256u tile, BK=32 -----------
// Occupancy-preserving depth-2 pipeline: 3 buffers x 24 KB = 72 KB -> still 2 blocks/CU.
// Per wave per tile: exactly 3 gl_lds (1 A + 2 B) -> steady-state s_waitcnt vmcnt(6)
// drains only tile t (issued 2 compute phases earlier); never drains to 0 mid-loop.
// 4-slot XOR chunk swizzle (slot = chunk ^ (row&3)) -> conflict-free ds_read_b128.
__global__ __launch_bounds__(512, 4) void k_xvo(const unsigned short* __restrict__ vot,
                                                const unsigned short* __restrict__ xbf,
                                                unsigned short* __restrict__ xvoT) {
    __shared__ __align__(16) unsigned short a_lds[3][128 * 32];   // 3 x 8 KB
    __shared__ __align__(16) unsigned short b_lds[3][256 * 32];   // 3 x 16 KB (total 72 KB)
    const int tid = threadIdx.x;
    const int w = tid >> 6, lane = tid & 63, l31 = lane & 31, half = lane >> 5;
    const int wm = w & 1, wn = w >> 1;
    const int ubase = blockIdx.x * 256;
    const int ebase = blockIdx.y * 128;
    const int b = blockIdx.z;

    f32x16 acc[2][2];
#pragma unroll
    for (int at = 0; at < 2; ++at)
#pragma unroll
        for (int bt = 0; bt < 2; ++bt)
#pragma unroll
            for (int i = 0; i < 16; ++i) acc[at][bt][i] = 0.f;

    const int sub4 = lane >> 2;                  // row within a 16-row stage group
    const int ga = (lane & 3) ^ (sub4 & 3);      // swizzled global chunk for this lane
    const unsigned short* Ap = vot + (size_t)(ebase + w * 16 + sub4) * DIM + ga * 8;
    const unsigned short* Bp = xbf + (size_t)(b * SEQ + ubase + w * 32 + sub4) * DIM + ga * 8;

    // 3 gl_lds per wave per tile — vmcnt counts below rely on this.
    auto stage = [&](int sb, int k0) {
        gl_lds16(Ap + k0, &a_lds[sb][(w * 16) * 32]);
        gl_lds16(Bp + k0, &b_lds[sb][(w * 32) * 32]);
        gl_lds16(Bp + (size_t)16 * DIM + k0, &b_lds[sb][(w * 32 + 16) * 32]);
    };

    const int NT = DIM / 32;                     // 32
    stage(0, 0);
    stage(1, 32);
    int cur = 0;
    for (int t = 0; t < NT; ++t) {
        if (t + 2 < NT) {
            int sb = cur - 1; if (sb < 0) sb = 2;            // (cur+2)%3
            stage(sb, (t + 2) * 32);
            asm volatile("s_waitcnt vmcnt(6)" ::: "memory"); // drain tile t only
        } else if (t + 1 < NT) {
            asm volatile("s_waitcnt vmcnt(3)" ::: "memory");
        } else {
            asm volatile("s_waitcnt vmcnt(0)" ::: "memory");
        }
        __builtin_amdgcn_s_barrier();
        asm volatile("" ::: "memory");

        const unsigned short* al = a_lds[cur];
        const unsigned short* bl = b_lds[cur];
        const int abase = (wm * 64 + l31) * 32;
        const int bbase = (wn * 64 + l31) * 32;
        __builtin_amdgcn_s_setprio(1);
#pragma unroll
        for (int ks = 0; ks < 2; ++ks) {
            const int soff = ((ks * 2 + half) ^ (l31 & 3)) * 8;
            bf16x8 a0 = *(const bf16x8*)&al[abase + soff];
            bf16x8 a1 = *(const bf16x8*)&al[abase + 1024 + soff];
            bf16x8 b0 = *(const bf16x8*)&bl[bbase + soff];
            bf16x8 b1 = *(const bf16x8*)&bl[bbase + 1024 + soff];
            acc[0][0] = __builtin_amdgcn_mfma_f32_32x32x16_bf16(a0, b0, acc[0][0], 0, 0, 0);
            acc[0][1] = __builtin_amdgcn_mfma_f32_32x32x16_bf16(a0, b1, acc[0][1], 0, 0, 0);
            acc[1][0] = __builtin_amdgcn_mfma_f32_32x32x16_bf16(a1, b0, acc[1][0], 0, 0, 0);
            acc[1][1] = __builtin_amdgcn_mfma_f32_32x32x16_bf16(a1, b1, acc[1][1], 0, 0, 0);
        }
        __builtin_amdgcn_s_setprio(0);
        asm volatile("" ::: "memory");
        __builtin_amdgcn_s_barrier();            // all reads of buf[cur] done before overwrite
        asm volatile("" ::: "memory");
        cur = (cur == 2) ? 0 : cur + 1;
    }
#pragma unroll
    for (int at = 0; at < 2; ++at)
#pragma unroll
        for (int bt = 0; bt < 2; ++bt)
#pragma unroll
            for (int reg = 0; reg < 16; ++reg) {
                int lr = wm * 64 + at * 32 + (reg & 3) + 8 * (reg >> 2) + 4 * half;
                int u = ubase + wn * 64 + bt * 32 + l31;
                xvoT[(size_t)(b * DIM + ebase + lr) * SEQ + u] = f2bf(acc[at][bt][reg]);
            }
}

// ---------------- K6 v4: out = (P @ xvoT^T)*(1/den). 128q x 256e tile, BK=32 -----------
// Same occupancy-preserving depth-2 pipeline as K5 v4. 1-D grid 512, XCD swizzle:
// xcd=p&7 owns rows 16*xcd..+15 (all 4 e-tiles co-located on one XCD's L2).
__global__ __launch_bounds__(512, 4) void k_pv(const unsigned short* __restrict__ P,
                                               const unsigned short* __restrict__ xvoT,
                                               const float* __restrict__ den_part,
                                               float* __restrict__ out) {
    __shared__ __align__(16) unsigned short a_lds[3][128 * 32];   // 3 x 8 KB
    __shared__ __align__(16) unsigned short b_lds[3][256 * 32];   // 3 x 16 KB
    __shared__ float rden[128];
    const int tid = threadIdx.x;
    const int w = tid >> 6, lane = tid & 63, l31 = lane & 31, half = lane >> 5;
    const int wm = w & 1, wn = w >> 1;

    const int p = blockIdx.x;
    const int xcd = p & 7, t0 = p >> 3;
    const int rowtile = xcd * 16 + (t0 >> 2);    // 0..127
    const int etile = t0 & 3;                    // 0..3
    const int rowbase = rowtile * 128;           // global q-row
    const int ebase = etile * 256;
    const int b = rowbase >> 12;

    if (tid < 128) {
        float s = 0.f;
#pragma unroll
        for (int i = 0; i < 8; ++i) s += den_part[(size_t)i * MTOT + rowbase + tid];
        rden[tid] = 1.0f / s;
    }
    // den loads retired by data dep; drain the rden ds_write so it's visible at the
    // first s_barrier (gl_lds traffic only touches vmcnt).
    asm volatile("s_waitcnt lgkmcnt(0)" ::: "memory");

    f32x16 acc[2][2];
#pragma unroll
    for (int at = 0; at < 2; ++at)
#pragma unroll
        for (int bt = 0; bt < 2; ++bt)
#pragma unroll
            for (int i = 0; i < 16; ++i) acc[at][bt][i] = 0.f;

    const int sub4 = lane >> 2;
    const int ga = (lane & 3) ^ (sub4 & 3);
    const unsigned short* Ap = P + (size_t)(rowbase + w * 16 + sub4) * SEQ + ga * 8;
    const unsigned short* Bp = xvoT + (size_t)(b * DIM + ebase + w * 32 + sub4) * SEQ + ga * 8;

    auto stage = [&](int sb, int k0) {
        gl_lds16(Ap + k0, &a_lds[sb][(w * 16) * 32]);
        gl_lds16(Bp + k0, &b_lds[sb][(w * 32) * 32]);
        gl_lds16(Bp + (size_t)16 * SEQ + k0, &b_lds[sb][(w * 32 + 16) * 32]);
    };

    const int NT = SEQ / 32;                     // 128
    stage(0, 0);
    stage(1, 32);
    int cur = 0;
    for (int t = 0; t < NT; ++t) {
        if (t + 2 < NT) {
            int sb = cur - 1; if (sb < 0) sb = 2;            // (cur+2)%3
            stage(sb, (t + 2) * 32);
            asm volatile("s_waitcnt vmcnt(6)" ::: "memory"); // drain tile t only
        } else if (t + 1 < NT) {
            asm volatile("s_waitcnt vmcnt(3)" ::: "memory");
        } else {
            asm volatile("s_waitcnt vmcnt(0)" ::: "memory");
        }
        __builtin_amdgcn_s_barrier();
        asm volatile("" ::: "memory");

        const unsigned short* al = a_lds[cur];
        const unsigned short* bl = b_lds[cur];
        const int abase = (wm * 64 + l31) * 32;
        const int bbase = (wn * 64 + l31) * 32;
        __builtin_amdgcn_s_setprio(1);
#pragma unroll
        for (int ks = 0; ks < 2; ++ks) {
            const int soff = ((ks * 2 + half) ^ (l31 & 3)) * 8;
            bf16x8 a0 = *(const bf16x8*)&al[abase + soff];
            bf16x8 a1 = *(const bf16x8*)&al[abase + 1024 + soff];
            bf16x8 b0 = *(const bf16x8*)&bl[bbase + soff];
            bf16x8 b1 = *(const bf16x8*)&bl[bbase + 1024 + soff];
            acc[0][0] = __builtin_amdgcn_mfma_f32_32x32x16_bf16(a0, b0, acc[0][0], 0, 0, 0);
            acc[0][1] = __builtin_amdgcn_mfma_f32_32x32x16_bf16(a0, b1, acc[0][1], 0, 0, 0);
            acc[1][0] = __builtin_amdgcn_mfma_f32_32x32x16_bf16(a1, b0, acc[1][0], 0, 0, 0);
            acc[1][1] = __builtin_amdgcn_mfma_f32_32x32x16_bf16(a1, b1, acc[1][1], 0, 0, 0);
        }
        __builtin_amdgcn_s_setprio(0);
        asm volatile("" ::: "memory");
        __builtin_amdgcn_s_barrier();
        asm volatile("" ::: "memory");
        cur = (cur == 2) ? 0 : cur + 1;
    }
#pragma unroll
    for (int at = 0; at < 2; ++at)
#pragma unroll
        for (int bt = 0; bt < 2; ++bt)
#pragma unroll
            for (int reg = 0; reg < 16; ++reg) {
                int lr = wm * 64 + at * 32 + (reg & 3) + 8 * (reg >> 2) + 4 * half;
                int e = ebase + wn * 64 + bt * 32 + l31;
                out[(size_t)(rowbase + lr) * DIM + e] = acc[at][bt][reg] * rden[lr];
            }
}

extern "C" void kernel_launch(void* const* d_in, const int* in_sizes, int n_in,
                              void* d_out, int out_size, void* d_ws, size_t ws_size,
                              hipStream_t stream) {
    const float* x  = (const float*)d_in[0];
    const float* Q  = (const float*)d_in[1];
    const float* K  = (const float*)d_in[2];
    const float* VO = (const float*)d_in[3];
    float* out = (float*)d_out;

    char* ws = (char*)d_ws;
    unsigned short* wqk  = (unsigned short*)(ws + 0);           // 64x1024 bf16        128 KB
    unsigned short* vot  = (unsigned short*)(ws + 131072);      // 1024x1024 bf16        2 MB
    unsigned short* xqk  = (unsigned short*)(ws + 2228224);     // 16384x64 bf16         2 MB
    unsigned short* xbf  = (unsigned short*)(ws + 4325376);     // 16384x1024 bf16      32 MB
    unsigned short* xvoT = (unsigned short*)(ws + 37879808);    // 4x1024x4096 bf16     32 MB
    float*          denp = (float*)(ws + 71434240);             // 8x16384 fp32        512 KB
    unsigned short* P    = (unsigned short*)(ws + 71958528);    // 4x4096x4096 bf16    128 MB

    k_cvt_qk<<<256, 256, 0, stream>>>(Q, K, wqk);
    k_transpose_cvt<<<dim3(16, 16, 1), 256, 0, stream>>>(VO, vot, 1024, 1024);
    k_xbf<<<8192, 256, 0, stream>>>(x, xbf);
    k_proj<<<128, 256, 0, stream>>>(xbf, wqk, xqk);
    k_score<<<dim3(SEQ / 64, 8, BATCH), 256, 0, stream>>>(xqk, P, denp);
    k_xvo<<<dim3(16, 8, BATCH), 512, 0, stream>>>(vot, xbf, xvoT);
    k_pv<<<dim3(512, 1, 1), 512, 0, stream>>>(P, xvoT, denp, out);
}

// Round 3
// 328.408 us; speedup vs baseline: 1.1934x; 1.1013x over previous
//
#include <hip/hip_runtime.h>
#include <hip/hip_bf16.h>

#define DIM  1024
#define RANK 32
#define BATCH 4
#define SEQ  4096
#define MTOT (BATCH * SEQ)   // 16384

typedef short bf16x8 __attribute__((ext_vector_type(8)));          // MFMA A/B frag (8 bf16)
typedef float f32x4 __attribute__((ext_vector_type(4)));           // 16x16 MFMA C/D frag
typedef float f32x16 __attribute__((ext_vector_type(16)));         // 32x32 MFMA C/D frag
typedef unsigned short ushort8v __attribute__((ext_vector_type(8)));
typedef unsigned int uint2v __attribute__((ext_vector_type(2)));

__device__ inline unsigned short f2bf(float f) {
    union { float f; unsigned int u; } v; v.f = f;
    return (unsigned short)((v.u + 0x7FFFu + ((v.u >> 16) & 1u)) >> 16);  // RNE
}

__device__ inline unsigned int pk_bf16(float a, float b) {
    __hip_bfloat162 h = __float22bfloat162_rn(make_float2(a, b));
    unsigned int u; __builtin_memcpy(&u, &h, 4);
    return u;
}

// async global->LDS, 16B per lane; data lands at lds_base + lane*16 (wave-uniform base)
__device__ inline void gl_lds16(const unsigned short* g, unsigned short* l) {
    __builtin_amdgcn_global_load_lds(
        (const __attribute__((address_space(1))) unsigned int*)g,
        (__attribute__((address_space(3))) unsigned int*)l, 16, 0, 0);
}

// ---------------- K0: pack Q*SC, K (fp32 32x1024 each) -> wqk bf16 (64x1024) -----------
__global__ __launch_bounds__(256) void k_cvt_qk(const float* __restrict__ Q,
                                                const float* __restrict__ K,
                                                unsigned short* __restrict__ wqk) {
    int i = blockIdx.x * 256 + threadIdx.x;        // 65536 total
    int row = i >> 10, col = i & 1023;
    const float SC = 0.045084220027779984f;        // 1/(32*ln2)
    float v = (row < RANK) ? Q[row * DIM + col] * SC : K[(row - RANK) * DIM + col];
    wqk[i] = f2bf(v);
}

// ---------------- K1: tiled transpose + fp32->bf16 (VO -> vot[e][d]) -------------------
__global__ __launch_bounds__(256) void k_transpose_cvt(const float* __restrict__ in,
                                                       unsigned short* __restrict__ out,
                                                       int R, int C) {
    __shared__ float tile[64][65];
    const int tid = threadIdx.x;
    const int c0 = blockIdx.x * 64, r0 = blockIdx.y * 64;
    {
        int c = (tid & 15) * 4;
#pragma unroll
        for (int i = 0; i < 4; ++i) {
            int r = (tid >> 4) + i * 16;
            f32x4 v = *(const f32x4*)(in + (size_t)(r0 + r) * C + c0 + c);
            tile[r][c + 0] = v[0]; tile[r][c + 1] = v[1];
            tile[r][c + 2] = v[2]; tile[r][c + 3] = v[3];
        }
    }
    __syncthreads();
    {
        int r = (tid & 15) * 4;
#pragma unroll
        for (int i = 0; i < 4; ++i) {
            int c = (tid >> 4) + i * 16;
            unsigned short o0 = f2bf(tile[r + 0][c]), o1 = f2bf(tile[r + 1][c]);
            unsigned short o2 = f2bf(tile[r + 2][c]), o3 = f2bf(tile[r + 3][c]);
            unsigned short* p = out + (size_t)(c0 + c) * R + r0 + r;
            p[0] = o0; p[1] = o1; p[2] = o2; p[3] = o3;
        }
    }
}

// ---------------- K2: x fp32 -> xbf bf16, row-major passthrough ------------------------
__global__ __launch_bounds__(256) void k_xbf(const float* __restrict__ x,
                                             unsigned short* __restrict__ xbf) {
    size_t i = ((size_t)blockIdx.x * 256 + threadIdx.x) * 8;
    f32x4 v0 = *(const f32x4*)(x + i);
    f32x4 v1 = *(const f32x4*)(x + i + 4);
    ushort8v o;
    o[0] = f2bf(v0[0]); o[1] = f2bf(v0[1]); o[2] = f2bf(v0[2]); o[3] = f2bf(v0[3]);
    o[4] = f2bf(v1[0]); o[5] = f2bf(v1[1]); o[6] = f2bf(v1[2]); o[7] = f2bf(v1[3]);
    *(ushort8v*)(xbf + i) = o;
}

// ---------------- K3: xqk = xbf @ wqk^T  (M=16384, N=64, K=1024), bf16 out -------------
__global__ __launch_bounds__(256) void k_proj(const unsigned short* __restrict__ xbf,
                                              const unsigned short* __restrict__ wqk,
                                              unsigned short* __restrict__ xqk) {
    __shared__ __align__(16) unsigned short a_lds[128 * 32];
    __shared__ __align__(16) unsigned short w_lds[64 * 32];
    const int tid = threadIdx.x;
    const int w = tid >> 6, lane = tid & 63, l15 = lane & 15, quad = lane >> 4;
    const int wm = w & 1, wn = w >> 1;
    const int rowbase = blockIdx.x * 128;

    f32x4 acc[4][2];
#pragma unroll
    for (int mt = 0; mt < 4; ++mt)
#pragma unroll
        for (int nt = 0; nt < 2; ++nt) acc[mt][nt] = (f32x4){0.f, 0.f, 0.f, 0.f};

    const unsigned short* Ab = xbf + (size_t)(rowbase + w * 32 + (lane >> 2)) * DIM + (lane & 3) * 8;
    const unsigned short* Wb = wqk + (size_t)(w * 16 + (lane >> 2)) * DIM + (lane & 3) * 8;

    for (int k0 = 0; k0 < DIM; k0 += 32) {
        gl_lds16(Ab + k0, &a_lds[(w * 32) * 32]);
        gl_lds16(Ab + (size_t)16 * DIM + k0, &a_lds[(w * 32 + 16) * 32]);
        gl_lds16(Wb + k0, &w_lds[(w * 16) * 32]);
        __syncthreads();
        bf16x8 am[4], bn[2];
#pragma unroll
        for (int mt = 0; mt < 4; ++mt)
            am[mt] = *(const bf16x8*)&a_lds[(wm * 64 + mt * 16 + l15) * 32 + quad * 8];
#pragma unroll
        for (int nt = 0; nt < 2; ++nt)
            bn[nt] = *(const bf16x8*)&w_lds[(wn * 32 + nt * 16 + l15) * 32 + quad * 8];
#pragma unroll
        for (int mt = 0; mt < 4; ++mt)
#pragma unroll
            for (int nt = 0; nt < 2; ++nt)
                acc[mt][nt] = __builtin_amdgcn_mfma_f32_16x16x32_bf16(am[mt], bn[nt], acc[mt][nt], 0, 0, 0);
        __syncthreads();
    }
#pragma unroll
    for (int mt = 0; mt < 4; ++mt)
#pragma unroll
        for (int nt = 0; nt < 2; ++nt)
#pragma unroll
            for (int r = 0; r < 4; ++r) {
                int grow = rowbase + wm * 64 + mt * 16 + quad * 4 + r;
                xqk[(size_t)grow * 64 + wn * 32 + nt * 16 + l15] = f2bf(acc[mt][nt][r]);
            }
}

// ---------------- K4: P = exp2(xq . xk) bf16 (materialized), den partials --------------
__global__ __launch_bounds__(256) void k_score(const unsigned short* __restrict__ xqk,
                                               unsigned short* __restrict__ P,
                                               float* __restrict__ den_part) {
    __shared__ __align__(16) unsigned short xk_lds[128 * 32];
    __shared__ __align__(16) unsigned short p_lds[64 * 136];
    __shared__ float denp[4][64];
    const int tid = threadIdx.x;
    const int w = tid >> 6, lane = tid & 63, l31 = lane & 31, half = lane >> 5;
    const int qbase = blockIdx.x * 64;
    const int kc = blockIdx.y;
    const int b = blockIdx.z;

    bf16x8 bq[2][2];
#pragma unroll
    for (int qt = 0; qt < 2; ++qt) {
        const unsigned short* base = xqk + (size_t)(b * SEQ + qbase + qt * 32 + l31) * 64 + half * 8;
        bq[qt][0] = *(const bf16x8*)(base);
        bq[qt][1] = *(const bf16x8*)(base + 16);
    }
    float dacc[2] = {0.f, 0.f};

    const unsigned short* XKb = xqk + (size_t)(b * SEQ + kc * 512 + w * 32 + (lane >> 2)) * 64 + 32 + (lane & 3) * 8;

    for (int it = 0; it < 4; ++it) {
        const int kkey = kc * 512 + it * 128;
        gl_lds16(XKb + (size_t)(it * 128) * 64, &xk_lds[(w * 32) * 32]);
        gl_lds16(XKb + (size_t)(it * 128 + 16) * 64, &xk_lds[(w * 32 + 16) * 32]);
        __syncthreads();

        bf16x8 ak0 = *(const bf16x8*)&xk_lds[(w * 32 + l31) * 32 + half * 8];
        bf16x8 ak1 = *(const bf16x8*)&xk_lds[(w * 32 + l31) * 32 + 16 + half * 8];
        f32x16 z;
#pragma unroll
        for (int i = 0; i < 16; ++i) z[i] = 0.f;
#pragma unroll
        for (int qt = 0; qt < 2; ++qt) {
            f32x16 sc = __builtin_amdgcn_mfma_f32_32x32x16_bf16(ak0, bq[qt][0], z, 0, 0, 0);
            sc = __builtin_amdgcn_mfma_f32_32x32x16_bf16(ak1, bq[qt][1], sc, 0, 0, 0);
#pragma unroll
            for (int g = 0; g < 4; ++g) {
                float e0 = exp2f(sc[4 * g + 0]), e1 = exp2f(sc[4 * g + 1]);
                float e2 = exp2f(sc[4 * g + 2]), e3 = exp2f(sc[4 * g + 3]);
                dacc[qt] += (e0 + e1) + (e2 + e3);
                uint2v dw; dw[0] = pk_bf16(e0, e1); dw[1] = pk_bf16(e2, e3);
                *(uint2v*)&p_lds[(qt * 32 + l31) * 136 + w * 32 + g * 8 + half * 4] = dw;
            }
        }
        __syncthreads();
#pragma unroll
        for (int i = 0; i < 4; ++i) {
            int row = i * 16 + (tid >> 4);
            int col = (tid & 15) * 8;
            ushort8v v = *(const ushort8v*)&p_lds[row * 136 + col];
            *(ushort8v*)(P + (size_t)(b * SEQ + qbase + row) * SEQ + kkey + col) = v;
        }
    }
#pragma unroll
    for (int qt = 0; qt < 2; ++qt) {
        float d = dacc[qt];
        d += __shfl_xor(d, 32);
        if (half == 0) denp[w][qt * 32 + l31] = d;
    }
    __syncthreads();
    if (tid < 64) {
        float s = denp[0][tid] + denp[1][tid] + denp[2][tid] + denp[3][tid];
        den_part[(size_t)kc * MTOT + b * SEQ + qbase + tid] = s;
    }
}

// ---------------- K5 (round-0): xvoT[b][e][u] = (x @ VO)^T. 128e x 256u, BK=64 ---------
// Proven single-buffer 2-barrier structure, 48 KB LDS, 2 blocks/CU.
// XOR chunk swizzle: staged slot s holds global chunk s^(row&7); frag read uses
// slot (ks*2+half)^(l31&7) -> conflict-free b128 (8 bank-cycles).
__global__ __launch_bounds__(512, 4) void k_xvo(const unsigned short* __restrict__ vot,
                                                const unsigned short* __restrict__ xbf,
                                                unsigned short* __restrict__ xvoT) {
    __shared__ __align__(16) unsigned short a_lds[128 * 64];   // 128 e-rows x 128B
    __shared__ __align__(16) unsigned short b_lds[256 * 64];   // 256 u-rows x 128B
    const int tid = threadIdx.x;
    const int w = tid >> 6, lane = tid & 63, l31 = lane & 31, half = lane >> 5;
    const int wm = w & 1, wn = w >> 1;
    const int ubase = blockIdx.x * 256;
    const int ebase = blockIdx.y * 128;
    const int b = blockIdx.z;

    f32x16 acc[2][2];
#pragma unroll
    for (int at = 0; at < 2; ++at)
#pragma unroll
        for (int bt = 0; bt < 2; ++bt)
#pragma unroll
            for (int i = 0; i < 16; ++i) acc[at][bt][i] = 0.f;

    const int sub = lane >> 3;                 // 0..7 rows within a stage call
    const int g = (lane & 7) ^ (sub & 7);      // swizzled global chunk for this lane
    const int Ra = w * 16 + sub;               // A rows (c adds 8; &7 invariant)
    const int Rb = w * 32 + sub;               // B rows (c adds 8)
    const unsigned short* Ap = vot + (size_t)(ebase + Ra) * DIM + g * 8;
    const unsigned short* Bp = xbf + (size_t)(b * SEQ + ubase + Rb) * DIM + g * 8;

    for (int k0 = 0; k0 < DIM; k0 += 64) {
#pragma unroll
        for (int c = 0; c < 2; ++c)
            gl_lds16(Ap + (size_t)(c * 8) * DIM + k0, &a_lds[(w * 16 + c * 8) * 64]);
#pragma unroll
        for (int c = 0; c < 4; ++c)
            gl_lds16(Bp + (size_t)(c * 8) * DIM + k0, &b_lds[(w * 32 + c * 8) * 64]);
        __syncthreads();

        const int abase = (wm * 64 + l31) * 64;
        const int bbase = (wn * 64 + l31) * 64;
#pragma unroll
        for (int ks = 0; ks < 4; ++ks) {
            const int soff = ((ks * 2 + half) ^ (l31 & 7)) * 8;
            bf16x8 a0 = *(const bf16x8*)&a_lds[abase + soff];
            bf16x8 a1 = *(const bf16x8*)&a_lds[abase + 2048 + soff];
            bf16x8 b0 = *(const bf16x8*)&b_lds[bbase + soff];
            bf16x8 b1 = *(const bf16x8*)&b_lds[bbase + 2048 + soff];
            acc[0][0] = __builtin_amdgcn_mfma_f32_32x32x16_bf16(a0, b0, acc[0][0], 0, 0, 0);
            acc[0][1] = __builtin_amdgcn_mfma_f32_32x32x16_bf16(a0, b1, acc[0][1], 0, 0, 0);
            acc[1][0] = __builtin_amdgcn_mfma_f32_32x32x16_bf16(a1, b0, acc[1][0], 0, 0, 0);
            acc[1][1] = __builtin_amdgcn_mfma_f32_32x32x16_bf16(a1, b1, acc[1][1], 0, 0, 0);
        }
        __syncthreads();
    }
#pragma unroll
    for (int at = 0; at < 2; ++at)
#pragma unroll
        for (int bt = 0; bt < 2; ++bt)
#pragma unroll
            for (int reg = 0; reg < 16; ++reg) {
                int lr = wm * 64 + at * 32 + (reg & 3) + 8 * (reg >> 2) + 4 * half;
                int u = ubase + wn * 64 + bt * 32 + l31;
                xvoT[(size_t)(b * DIM + ebase + lr) * SEQ + u] = f2bf(acc[at][bt][reg]);
            }
}

// ---------------- K6 v5: out = (P @ xvoT^T)*(1/den). 128q x 256e tile, BK=64 -----------
// Asymmetric double-buffer: A (the HBM-latency P stream, 16 KB/tile) is double-buffered
// and its stage for tile t+1 issues at the START of tile t's compute (~600 cy in-flight
// cover). B (the 2 MB XCD-local L2-hot xvoT panel) stays single-buffered: staged after a
// cheap lgkmcnt-only barrier, drained with vmcnt(0) (~L2 latency only) before barrier-2.
// LDS = 2x16 + 32 + rden = 64.5 KB -> keeps 2 blocks/CU. Same proven conflict-free
// XOR-8 chunk swizzle and frag layout as round 0.
__global__ __launch_bounds__(512, 4) void k_pv(const unsigned short* __restrict__ P,
                                               const unsigned short* __restrict__ xvoT,
                                               const float* __restrict__ den_part,
                                               float* __restrict__ out) {
    __shared__ __align__(16) unsigned short a_lds[2][128 * 64];   // 2 x 16 KB (P tiles)
    __shared__ __align__(16) unsigned short b_lds[256 * 64];      // 32 KB (xvoT tile)
    __shared__ float rden[128];
    const int tid = threadIdx.x;
    const int w = tid >> 6, lane = tid & 63, l31 = lane & 31, half = lane >> 5;
    const int wm = w & 1, wn = w >> 1;

    const int p = blockIdx.x;
    const int xcd = p & 7, t0 = p >> 3;
    const int rowtile = xcd * 16 + (t0 >> 2);   // 0..127
    const int etile = t0 & 3;                   // 0..3
    const int rowbase = rowtile * 128;          // global q-row
    const int ebase = etile * 256;
    const int b = rowbase >> 12;

    if (tid < 128) {
        float s = 0.f;
#pragma unroll
        for (int i = 0; i < 8; ++i) s += den_part[(size_t)i * MTOT + rowbase + tid];
        rden[tid] = 1.0f / s;
    }

    f32x16 acc[2][2];
#pragma unroll
    for (int at = 0; at < 2; ++at)
#pragma unroll
        for (int bt = 0; bt < 2; ++bt)
#pragma unroll
            for (int i = 0; i < 16; ++i) acc[at][bt][i] = 0.f;

    const int sub = lane >> 3;
    const int g = (lane & 7) ^ (sub & 7);
    const unsigned short* Ap = P + (size_t)(rowbase + w * 16 + sub) * SEQ + g * 8;
    const unsigned short* Bp = xvoT + (size_t)(b * DIM + ebase + w * 32 + sub) * SEQ + g * 8;

    // Each wave stages its OWN rows (self-drained vmcnt -> barrier publishes).
    auto stageA = [&](int sb, int k0) {
#pragma unroll
        for (int c = 0; c < 2; ++c)
            gl_lds16(Ap + (size_t)(c * 8) * SEQ + k0, &a_lds[sb][(w * 16 + c * 8) * 64]);
    };
    auto stageB = [&](int k0) {
#pragma unroll
        for (int c = 0; c < 4; ++c)
            gl_lds16(Bp + (size_t)(c * 8) * SEQ + k0, &b_lds[(w * 32 + c * 8) * 64]);
    };

    const int NT = SEQ / 64;                    // 64
    stageA(0, 0);
    stageB(0);
    __syncthreads();                            // prologue: full drain + publish (also rden)

    int pb = 0;
    for (int t = 0; t < NT; ++t) {
        if (t + 1 < NT) stageA(pb ^ 1, (t + 1) * 64);   // A(t+1) flies during compute(t)

        const unsigned short* al = a_lds[pb];
        const int abase = (wm * 64 + l31) * 64;
        const int bbase = (wn * 64 + l31) * 64;
#pragma unroll
        for (int ks = 0; ks < 4; ++ks) {
            const int soff = ((ks * 2 + half) ^ (l31 & 7)) * 8;
            bf16x8 a0 = *(const bf16x8*)&al[abase + soff];
            bf16x8 a1 = *(const bf16x8*)&al[abase + 2048 + soff];
            bf16x8 b0 = *(const bf16x8*)&b_lds[bbase + soff];
            bf16x8 b1 = *(const bf16x8*)&b_lds[bbase + 2048 + soff];
            acc[0][0] = __builtin_amdgcn_mfma_f32_32x32x16_bf16(a0, b0, acc[0][0], 0, 0, 0);
            acc[0][1] = __builtin_amdgcn_mfma_f32_32x32x16_bf16(a0, b1, acc[0][1], 0, 0, 0);
            acc[1][0] = __builtin_amdgcn_mfma_f32_32x32x16_bf16(a1, b0, acc[1][0], 0, 0, 0);
            acc[1][1] = __builtin_amdgcn_mfma_f32_32x32x16_bf16(a1, b1, acc[1][1], 0, 0, 0);
        }
        // barrier-1: all waves' B-reads retired (reads are data-dep consumed by MFMA;
        // lgkmcnt(0) makes it explicit). NO vmem drain here - A(t+1) stays in flight.
        asm volatile("s_waitcnt lgkmcnt(0)" ::: "memory");
        __builtin_amdgcn_s_barrier();
        asm volatile("" ::: "memory");

        if (t + 1 < NT) {
            stageB((t + 1) * 64);               // L2-hot panel: short drain below
            asm volatile("s_waitcnt vmcnt(0)" ::: "memory");
        }
        __builtin_amdgcn_s_barrier();           // barrier-2: publish A(t+1) + B(t+1)
        asm volatile("" ::: "memory");
        pb ^= 1;
    }
#pragma unroll
    for (int at = 0; at < 2; ++at)
#pragma unroll
        for (int bt = 0; bt < 2; ++bt)
#pragma unroll
            for (int reg = 0; reg < 16; ++reg) {
                int lr = wm * 64 + at * 32 + (reg & 3) + 8 * (reg >> 2) + 4 * half;
                int e = ebase + wn * 64 + bt * 32 + l31;
                out[(size_t)(rowbase + lr) * DIM + e] = acc[at][bt][reg] * rden[lr];
            }
}

extern "C" void kernel_launch(void* const* d_in, const int* in_sizes, int n_in,
                              void* d_out, int out_size, void* d_ws, size_t ws_size,
                              hipStream_t stream) {
    const float* x  = (const float*)d_in[0];
    const float* Q  = (const float*)d_in[1];
    const float* K  = (const float*)d_in[2];
    const float* VO = (const float*)d_in[3];
    float* out = (float*)d_out;

    char* ws = (char*)d_ws;
    unsigned short* wqk  = (unsigned short*)(ws + 0);           // 64x1024 bf16        128 KB
    unsigned short* vot  = (unsigned short*)(ws + 131072);      // 1024x1024 bf16        2 MB
    unsigned short* xqk  = (unsigned short*)(ws + 2228224);     // 16384x64 bf16         2 MB
    unsigned short* xbf  = (unsigned short*)(ws + 4325376);     // 16384x1024 bf16      32 MB
    unsigned short* xvoT = (unsigned short*)(ws + 37879808);    // 4x1024x4096 bf16     32 MB
    float*          denp = (float*)(ws + 71434240);             // 8x16384 fp32        512 KB
    unsigned short* P    = (unsigned short*)(ws + 71958528);    // 4x4096x4096 bf16    128 MB

    k_cvt_qk<<<256, 256, 0, stream>>>(Q, K, wqk);
    k_transpose_cvt<<<dim3(16, 16, 1), 256, 0, stream>>>(VO, vot, 1024, 1024);
    k_xbf<<<8192, 256, 0, stream>>>(x, xbf);
    k_proj<<<128, 256, 0, stream>>>(xbf, wqk, xqk);
    k_score<<<dim3(SEQ / 64, 8, BATCH), 256, 0, stream>>>(xqk, P, denp);
    k_xvo<<<dim3(16, 8, BATCH), 512, 0, stream>>>(vot, xbf, xvoT);
    k_pv<<<dim3(512, 1, 1), 512, 0, stream>>>(P, xvoT, denp, out);
}